// Round 8
// baseline (204.509 us; speedup 1.0000x reference)
//
#include <hip/hip_runtime.h>
#include <hip/hip_bf16.h>

#define N_ELEM 1000000
#define D 128
#define S_SEG 65536
#define SEGW 32           // segments per wave: NBLK*4 waves * SEGW == S_SEG
#define NBLK 512          // 2048 waves total -> ~2048 DRAM streams (~8/channel)
#define NEG_BIG (-1e30f)

// 32-lane xor-reduce (offsets 1..16 never cross the 32-lane half).
__device__ __forceinline__ float halfReduce(float d) {
    #pragma unroll
    for (int off = 1; off <= 16; off <<= 1)
        d += __shfl_xor(d, off, 64);
    return d;
}

__device__ __forceinline__ float dot4(float4 v, float4 w) {
    return fmaf(v.x, w.x, fmaf(v.y, w.y, fmaf(v.z, w.z, v.w * w.w)));
}

// One online-softmax step: state (m,l,a) absorbs (d, v). valid==false => no-op
// (branchless: p forced 0, m unchanged, scale = exp(0) = 1; NEG_BIG sentinel
// keeps all subtractions finite -> no NaN; masked-row v is finite garbage
// multiplied by p=0).
__device__ __forceinline__ void osm_step(float& m, float& l, float4& a,
                                         float d, float4 v, bool valid) {
    float mn = valid ? fmaxf(m, d) : m;
    float scale = __expf(m - mn);
    float p = valid ? __expf(d - mn) : 0.f;
    m = mn;
    l = fmaf(l, scale, p);
    a.x = fmaf(a.x, scale, p * v.x);
    a.y = fmaf(a.y, scale, p * v.y);
    a.z = fmaf(a.z, scale, p * v.z);
    a.w = fmaf(a.w, scale, p * v.w);
}

// Merge state 2 into state 1 (safe for empty states thanks to finite sentinel).
__device__ __forceinline__ void osm_merge(float& m1, float& l1, float4& a1,
                                          float m2, float l2, float4 a2) {
    float m = fmaxf(m1, m2);
    float s1 = __expf(m1 - m), s2 = __expf(m2 - m);
    l1 = l1 * s1 + l2 * s2;
    a1.x = a1.x * s1 + a2.x * s2;
    a1.y = a1.y * s1 + a2.y * s2;
    a1.z = a1.z * s1 + a2.z * s2;
    a1.w = a1.w * s1 + a2.w * s2;
    m1 = m;
}

// K1: one wave owns SEGW consecutive segments (~244 KB contiguous stream);
// SINGLE streaming pass, online softmax + weighted accumulate fused.
// - 2048 total waves -> few DRAM streams per HBM channel (row-buffer friendly),
//   vs 8192 streams previously (suspected row-thrash at 3.4 TB/s).
// - distance-2 software pipeline: 4 independent 1KB wave-loads in flight
//   (~32 KB outstanding/CU >= 3x Little's-law need at 2 waves/SIMD).
// - inline bounds: lanes 0..32 binary-search the wave's 33 segment offsets,
//   broadcast via __shfl.
// emb touches HBM exactly once; h written once; no atomics, no zero-init.
__global__ __launch_bounds__(256) void k_fused(
        const float* __restrict__ emb, const int* __restrict__ seg,
        const float* __restrict__ watt, float* __restrict__ out) {
    const int lane = threadIdx.x & 63;
    const int half = lane >> 5;          // row parity this lane covers
    const int hl   = lane & 31;          // lane within half: dims 4*hl..4*hl+3
    const int wid  = blockIdx.x * 4 + (threadIdx.x >> 6);
    const float4 wv = reinterpret_cast<const float4*>(watt)[hl];
    const float4* emb4 = reinterpret_cast<const float4*>(emb);
    float4* out4 = reinterpret_cast<float4*>(out);

    const int s0 = wid * SEGW;
    // lane i (i<=SEGW) computes lower_bound(seg, s0+i); others idle.
    int lo = 0;
    if (lane <= SEGW) {
        const int target = s0 + lane;
        int hi = N_ELEM;
        while (lo < hi) {
            int mid = (lo + hi) >> 1;
            if (seg[mid] < target) lo = mid + 1; else hi = mid;
        }
    }

    #pragma unroll 1
    for (int si = 0; si < SEGW; ++si) {
        const int beg = __shfl(lo, si, 64);
        const int end = __shfl(lo, si + 1, 64);
        float  mA = NEG_BIG, lA = 0.f; float4 aA = {0.f, 0.f, 0.f, 0.f};
        float  mB = NEG_BIG, lB = 0.f; float4 aB = {0.f, 0.f, 0.f, 0.f};
        if (beg < end) {
            // distance-2 pipeline prologue: rows beg..beg+7 (clamped, masked later)
            float4 c0 = emb4[(size_t)min(beg +     half, N_ELEM - 1) * 32 + hl];
            float4 c1 = emb4[(size_t)min(beg + 2 + half, N_ELEM - 1) * 32 + hl];
            float4 c2 = emb4[(size_t)min(beg + 4 + half, N_ELEM - 1) * 32 + hl];
            float4 c3 = emb4[(size_t)min(beg + 6 + half, N_ELEM - 1) * 32 + hl];
            #pragma unroll 1
            for (int e = beg; e < end; e += 4) {
                // issue loads for iteration e+8 (may over-read into next segments;
                // clamped in-bounds, masked out, L1-hot on re-read)
                float4 n0 = emb4[(size_t)min(e + 8  + half, N_ELEM - 1) * 32 + hl];
                float4 n1 = emb4[(size_t)min(e + 10 + half, N_ELEM - 1) * 32 + hl];
                float d0 = halfReduce(dot4(c0, wv));
                float d1 = halfReduce(dot4(c1, wv));
                osm_step(mA, lA, aA, d0, c0, (e +     half) < end);
                osm_step(mB, lB, aB, d1, c1, (e + 2 + half) < end);
                c0 = c2; c1 = c3; c2 = n0; c3 = n1;
            }
        }
        // merge B into A, then cross-half merge via shfl_xor(32)
        osm_merge(mA, lA, aA, mB, lB, aB);
        float  mo  = __shfl_xor(mA, 32, 64);
        float  lo2 = __shfl_xor(lA, 32, 64);
        float4 ao;
        ao.x = __shfl_xor(aA.x, 32, 64);
        ao.y = __shfl_xor(aA.y, 32, 64);
        ao.z = __shfl_xor(aA.z, 32, 64);
        ao.w = __shfl_xor(aA.w, 32, 64);
        osm_merge(mA, lA, aA, mo, lo2, ao);
        float inv = (lA > 0.f) ? 1.0f / lA : 0.f;        // empty segment -> zeros
        if (half == 0) {
            float4 r = {aA.x * inv, aA.y * inv, aA.z * inv, aA.w * inv};
            out4[(size_t)(s0 + si) * 32 + hl] = r;
        }
    }
}

// K2: out[s,:] = h[s,:] @ w_out^T, in place per 128-row tile.
// LDS-staged, transposed with +4 padding to dodge bank conflicts.
#define PAD 132
__global__ __launch_bounds__(256) void k_proj(
        float* __restrict__ out, const float* __restrict__ wout) {
    __shared__ float As[128 * PAD];  // As[k*PAD + r] = h[r0+r][k]
    __shared__ float Bs[128 * PAD];  // Bs[k*PAD + j] = wout[j][k]
    const int tid = threadIdx.x;
    const int r0 = blockIdx.x * 128;
    for (int idx = tid; idx < 128 * 128; idx += 256) {
        int a = idx >> 7, k = idx & 127;
        As[k * PAD + a] = out[(size_t)(r0 + a) * D + k];
        Bs[k * PAD + a] = wout[(size_t)a * D + k];
    }
    __syncthreads();
    const int tx = tid & 15, ty = tid >> 4;
    const int rr = ty * 8, cc = tx * 8;
    float acc[8][8] = {};
    for (int k = 0; k < 128; ++k) {
        float a[8], b[8];
        *reinterpret_cast<float4*>(&a[0]) = *reinterpret_cast<const float4*>(&As[k * PAD + rr]);
        *reinterpret_cast<float4*>(&a[4]) = *reinterpret_cast<const float4*>(&As[k * PAD + rr + 4]);
        *reinterpret_cast<float4*>(&b[0]) = *reinterpret_cast<const float4*>(&Bs[k * PAD + cc]);
        *reinterpret_cast<float4*>(&b[4]) = *reinterpret_cast<const float4*>(&Bs[k * PAD + cc + 4]);
        #pragma unroll
        for (int i = 0; i < 8; ++i)
            #pragma unroll
            for (int j = 0; j < 8; ++j)
                acc[i][j] = fmaf(a[i], b[j], acc[i][j]);
    }
    #pragma unroll
    for (int i = 0; i < 8; ++i) {
        float4 o0 = {acc[i][0], acc[i][1], acc[i][2], acc[i][3]};
        float4 o1 = {acc[i][4], acc[i][5], acc[i][6], acc[i][7]};
        *reinterpret_cast<float4*>(&out[(size_t)(r0 + rr + i) * D + cc])     = o0;
        *reinterpret_cast<float4*>(&out[(size_t)(r0 + rr + i) * D + cc + 4]) = o1;
    }
}

extern "C" void kernel_launch(void* const* d_in, const int* in_sizes, int n_in,
                              void* d_out, int out_size, void* d_ws, size_t ws_size,
                              hipStream_t stream) {
    const float* emb  = (const float*)d_in[0];
    const int*   seg  = (const int*)d_in[1];
    const float* watt = (const float*)d_in[3];
    const float* wout = (const float*)d_in[4];
    float* out = (float*)d_out;

    k_fused<<<NBLK, 256, 0, stream>>>(emb, seg, watt, out);
    k_proj <<<S_SEG / 128, 256, 0, stream>>>(out, wout);
}

// Round 9
// 178.705 us; speedup vs baseline: 1.1444x; 1.1444x over previous
//
#include <hip/hip_runtime.h>
#include <hip/hip_bf16.h>

#define N_ELEM 1000000
#define D 128
#define S_SEG 65536
#define SEGW 8            // segments per wave: NBLK*4 waves * SEGW == S_SEG
#define NBLK 2048         // 8192 waves (full-occupancy regime, best so far)
#define NEG_BIG (-1e30f)

// 32-lane xor-reduce (offsets 1..16 never cross the 32-lane half).
__device__ __forceinline__ float halfReduce(float d) {
    #pragma unroll
    for (int off = 1; off <= 16; off <<= 1)
        d += __shfl_xor(d, off, 64);
    return d;
}

__device__ __forceinline__ float dot4(float4 v, float4 w) {
    return fmaf(v.x, w.x, fmaf(v.y, w.y, fmaf(v.z, w.z, v.w * w.w)));
}

// One online-softmax step: state (m,l,a) absorbs (d, v). valid==false => no-op
// (branchless: p forced 0, m unchanged, scale = exp(0) = 1; NEG_BIG sentinel
// keeps all subtractions finite -> no NaN; masked-row v is finite garbage
// multiplied by p=0).
__device__ __forceinline__ void osm_step(float& m, float& l, float4& a,
                                         float d, float4 v, bool valid) {
    float mn = valid ? fmaxf(m, d) : m;
    float scale = __expf(m - mn);
    float p = valid ? __expf(d - mn) : 0.f;
    m = mn;
    l = fmaf(l, scale, p);
    a.x = fmaf(a.x, scale, p * v.x);
    a.y = fmaf(a.y, scale, p * v.y);
    a.z = fmaf(a.z, scale, p * v.z);
    a.w = fmaf(a.w, scale, p * v.w);
}

// Merge state 2 into state 1 (safe for empty states thanks to finite sentinel).
__device__ __forceinline__ void osm_merge(float& m1, float& l1, float4& a1,
                                          float m2, float l2, float4 a2) {
    float m = fmaxf(m1, m2);
    float s1 = __expf(m1 - m), s2 = __expf(m2 - m);
    l1 = l1 * s1 + l2 * s2;
    a1.x = a1.x * s1 + a2.x * s2;
    a1.y = a1.y * s1 + a2.y * s2;
    a1.z = a1.z * s1 + a2.z * s2;
    a1.w = a1.w * s1 + a2.w * s2;
    m1 = m;
}

// K1: one wave owns SEGW consecutive segments; SINGLE streaming pass.
// ROUND-9 EXPERIMENT: distance-2 software pipeline (4 KB in flight per wave:
// pairs {c0,c1}=iter i, {c2,c3}=iter i+1 landed/landing, {n0,n1}=iter i+2
// issued) at FULL wave count (8192) -- isolates per-wave MLP from R8's
// wave-count confound. launch_bounds(256,6) keeps >=6 waves/SIMD resident.
// emb touches HBM exactly once; h written once; no atomics, no zero-init.
__global__ __launch_bounds__(256, 6) void k_fused(
        const float* __restrict__ emb, const int* __restrict__ seg,
        const float* __restrict__ watt, float* __restrict__ out) {
    const int lane = threadIdx.x & 63;
    const int half = lane >> 5;          // row parity this lane covers
    const int hl   = lane & 31;          // lane within half: dims 4*hl..4*hl+3
    const int wid  = blockIdx.x * 4 + (threadIdx.x >> 6);
    const float4 wv = reinterpret_cast<const float4*>(watt)[hl];
    const float4* emb4 = reinterpret_cast<const float4*>(emb);
    float4* out4 = reinterpret_cast<float4*>(out);

    const int s0 = wid * SEGW;
    // lane i (i<=SEGW) computes lower_bound(seg, s0+i); others idle.
    int lo = 0;
    if (lane <= SEGW) {
        const int target = s0 + lane;
        int hi = N_ELEM;
        while (lo < hi) {
            int mid = (lo + hi) >> 1;
            if (seg[mid] < target) lo = mid + 1; else hi = mid;
        }
    }

    #pragma unroll 1
    for (int si = 0; si < SEGW; ++si) {
        const int beg = __shfl(lo, si, 64);
        const int end = __shfl(lo, si + 1, 64);
        float  mA = NEG_BIG, lA = 0.f; float4 aA = {0.f, 0.f, 0.f, 0.f};
        float  mB = NEG_BIG, lB = 0.f; float4 aB = {0.f, 0.f, 0.f, 0.f};
        if (beg < end) {
            // dist-2 prologue: rows beg..beg+7 (clamped; masked in consume)
            float4 c0 = emb4[(size_t)min(beg +     half, N_ELEM - 1) * 32 + hl];
            float4 c1 = emb4[(size_t)min(beg + 2 + half, N_ELEM - 1) * 32 + hl];
            float4 c2 = emb4[(size_t)min(beg + 4 + half, N_ELEM - 1) * 32 + hl];
            float4 c3 = emb4[(size_t)min(beg + 6 + half, N_ELEM - 1) * 32 + hl];
            #pragma unroll 1
            for (int e = beg; e < end; e += 4) {
                // issue loads for iteration e+8 (may over-read into next
                // segments; clamped in-bounds, masked out, L1-hot on re-read)
                float4 n0 = emb4[(size_t)min(e + 8  + half, N_ELEM - 1) * 32 + hl];
                float4 n1 = emb4[(size_t)min(e + 10 + half, N_ELEM - 1) * 32 + hl];
                float d0 = halfReduce(dot4(c0, wv));
                float d1 = halfReduce(dot4(c1, wv));
                osm_step(mA, lA, aA, d0, c0, (e +     half) < end);
                osm_step(mB, lB, aB, d1, c1, (e + 2 + half) < end);
                c0 = c2; c1 = c3; c2 = n0; c3 = n1;
            }
        }
        // merge B into A, then cross-half merge via shfl_xor(32)
        osm_merge(mA, lA, aA, mB, lB, aB);
        float  mo  = __shfl_xor(mA, 32, 64);
        float  lo2 = __shfl_xor(lA, 32, 64);
        float4 ao;
        ao.x = __shfl_xor(aA.x, 32, 64);
        ao.y = __shfl_xor(aA.y, 32, 64);
        ao.z = __shfl_xor(aA.z, 32, 64);
        ao.w = __shfl_xor(aA.w, 32, 64);
        osm_merge(mA, lA, aA, mo, lo2, ao);
        float inv = (lA > 0.f) ? 1.0f / lA : 0.f;        // empty segment -> zeros
        if (half == 0) {
            float4 r = {aA.x * inv, aA.y * inv, aA.z * inv, aA.w * inv};
            out4[(size_t)(s0 + si) * 32 + hl] = r;
        }
    }
}

// K2: out[s,:] = h[s,:] @ w_out^T, in place per 128-row tile.
// LDS-staged, transposed with +4 padding to dodge bank conflicts.
#define PAD 132
__global__ __launch_bounds__(256) void k_proj(
        float* __restrict__ out, const float* __restrict__ wout) {
    __shared__ float As[128 * PAD];  // As[k*PAD + r] = h[r0+r][k]
    __shared__ float Bs[128 * PAD];  // Bs[k*PAD + j] = wout[j][k]
    const int tid = threadIdx.x;
    const int r0 = blockIdx.x * 128;
    for (int idx = tid; idx < 128 * 128; idx += 256) {
        int a = idx >> 7, k = idx & 127;
        As[k * PAD + a] = out[(size_t)(r0 + a) * D + k];
        Bs[k * PAD + a] = wout[(size_t)a * D + k];
    }
    __syncthreads();
    const int tx = tid & 15, ty = tid >> 4;
    const int rr = ty * 8, cc = tx * 8;
    float acc[8][8] = {};
    for (int k = 0; k < 128; ++k) {
        float a[8], b[8];
        *reinterpret_cast<float4*>(&a[0]) = *reinterpret_cast<const float4*>(&As[k * PAD + rr]);
        *reinterpret_cast<float4*>(&a[4]) = *reinterpret_cast<const float4*>(&As[k * PAD + rr + 4]);
        *reinterpret_cast<float4*>(&b[0]) = *reinterpret_cast<const float4*>(&Bs[k * PAD + cc]);
        *reinterpret_cast<float4*>(&b[4]) = *reinterpret_cast<const float4*>(&Bs[k * PAD + cc + 4]);
        #pragma unroll
        for (int i = 0; i < 8; ++i)
            #pragma unroll
            for (int j = 0; j < 8; ++j)
                acc[i][j] = fmaf(a[i], b[j], acc[i][j]);
    }
    #pragma unroll
    for (int i = 0; i < 8; ++i) {
        float4 o0 = {acc[i][0], acc[i][1], acc[i][2], acc[i][3]};
        float4 o1 = {acc[i][4], acc[i][5], acc[i][6], acc[i][7]};
        *reinterpret_cast<float4*>(&out[(size_t)(r0 + rr + i) * D + cc])     = o0;
        *reinterpret_cast<float4*>(&out[(size_t)(r0 + rr + i) * D + cc + 4]) = o1;
    }
}

extern "C" void kernel_launch(void* const* d_in, const int* in_sizes, int n_in,
                              void* d_out, int out_size, void* d_ws, size_t ws_size,
                              hipStream_t stream) {
    const float* emb  = (const float*)d_in[0];
    const int*   seg  = (const int*)d_in[1];
    const float* watt = (const float*)d_in[3];
    const float* wout = (const float*)d_in[4];
    float* out = (float*)d_out;

    k_fused<<<NBLK, 256, 0, stream>>>(emb, seg, watt, out);
    k_proj <<<S_SEG / 128, 256, 0, stream>>>(out, wout);
}